// Round 8
// baseline (538.183 us; speedup 1.0000x reference)
//
#include <hip/hip_runtime.h>

#define NB 16
#define NTQ 256
#define NTK 256
#define ND 256
#define NF 36
#define NH 8
#define NDK 32
#define NSF 6

typedef __attribute__((ext_vector_type(8))) short short8;
typedef __attribute__((ext_vector_type(4))) float f32x4;
#define MFMA16(a,b,c) __builtin_amdgcn_mfma_f32_16x16x32_bf16(a,b,c,0,0,0)

// ---- workspace byte offsets ----
// RT: [b][80][256] bf16 (f'=2f: m*v, f'=2f+1: m)
#define RT_OFF   524288u
// projected Q/K hi/lo: [b][j][t][dk] bf16, 4MB each
#define QPH_OFF  (2u*1024*1024)
#define QPL_OFF  (6u*1024*1024)
#define KPH_OFF  (10u*1024*1024)
#define KPL_OFF  (14u*1024*1024)
// HD: fp32 [b][j][t][f]
#define HD_OFF   (18u*1024*1024)
// tail-election counters: 256 x u32 (zeroed by proj kernel each iteration)
#define CNT_OFF  (24u*1024*1024)

__device__ __forceinline__ short f2bf(float x){
    union { float f; unsigned u; } v; v.f = x;
    unsigned r = v.u + 0x7fffu + ((v.u >> 16) & 1u);
    return (short)(r >> 16);
}
__device__ __forceinline__ float bf2f(short s){
    union { float f; unsigned u; } v; v.u = ((unsigned)(unsigned short)s) << 16;
    return v.f;
}
__device__ __forceinline__ float fast_tanh(float x){
    float e = __expf(2.0f*x);
    return 1.0f - 2.0f/(e + 1.0f);
}
__device__ __forceinline__ short8 ld8(const short* p){ return *(const short8*)p; }

// hi/lo bf16 split of 8 consecutive floats (RNE hi, RNE residual lo)
__device__ __forceinline__ void cvt8(const float* __restrict__ p, short8& h8, short8& l8){
    f32x4 a = *(const f32x4*)p;
    f32x4 c = *(const f32x4*)(p + 4);
    #pragma unroll
    for (int i = 0; i < 4; ++i){
        short h0 = f2bf(a[i]); h8[i]   = h0; l8[i]   = f2bf(a[i] - bf2f(h0));
        short h1 = f2bf(c[i]); h8[4+i] = h1; l8[4+i] = f2bf(c[i] - bf2f(h1));
    }
}

// ---------------- kernel 1: projection GEMM (W staged in LDS) + RT pack + counter zero ----------------
__global__ __launch_bounds__(256, 4)
void imta_proj(const float* __restrict__ query, const float* __restrict__ key_ts,
               const float* __restrict__ Wq, const float* __restrict__ Wk,
               const float* __restrict__ mask, const float* __restrict__ value,
               char* __restrict__ wsb){
    const int bid = blockIdx.x, tid = threadIdx.x;
    if (bid >= 1024){
        const int rb = bid - 1024;
        if (rb == 0) ((unsigned*)(wsb + CNT_OFF))[tid] = 0u;   // zero tail counters
        const int x = rb & 15, b = rb >> 4;
        const int k = tid;
        short* rt = (short*)(wsb + RT_OFF) + b*80*256;
        #pragma unroll
        for (int r = 0; r < 5; ++r){
            const int fp = x*5 + r;
            const int f = fp >> 1;
            short o = 0;
            if (f < NF){
                float m = mask[(b*NTK + k)*NF + f];
                o = (fp & 1) ? f2bf(m) : f2bf(m * value[(b*NTK + k)*NF + f]);
            }
            rt[fp*256 + k] = o;
        }
        return;
    }
    const int b = bid >> 6, side = (bid >> 5) & 1, j = (bid >> 2) & 7;
    const int t0 = (bid & 3)*64;
    const int w = tid >> 6, lane = tid & 63;
    const int col = lane & 15, quad = lane >> 4;

    __shared__ __align__(16) short sW[2*32*264];     // hi | lo, [dk][264-padded d]
    short* const sWH = sW;
    short* const sWL = sW + 32*264;

    const float* __restrict__ X = side ? key_ts : query;
    const float* __restrict__ W = (side ? Wk : Wq) + (size_t)j*ND*NDK;
    short* OH = (short*)(wsb + (side ? KPH_OFF : QPH_OFF));
    short* OL = (short*)(wsb + (side ? KPL_OFF : QPL_OFF));

    {
        const int dk0 = (tid & 7)*4, dbase = tid >> 3;
        #pragma unroll
        for (int it = 0; it < 8; ++it){
            const int d = dbase + it*32;
            f32x4 wv = *(const f32x4*)(W + (size_t)d*NDK + dk0);
            #pragma unroll
            for (int i = 0; i < 4; ++i){
                short h = f2bf(wv[i]);
                sWH[(dk0 + i)*264 + d] = h;
                sWL[(dk0 + i)*264 + d] = f2bf(wv[i] - bf2f(h));
            }
        }
    }
    __syncthreads();

    const int row = t0 + w*16 + col;
    const float* xrow = X + (size_t)(b*NTQ + row)*ND;
    f32x4 acc[2]; acc[0] = (f32x4)0.f; acc[1] = (f32x4)0.f;
    #pragma unroll
    for (int kb = 0; kb < 8; ++kb){
        const int dko = kb*32 + quad*8;
        short8 ah, al;
        cvt8(xrow + dko, ah, al);
        #pragma unroll
        for (int nt = 0; nt < 2; ++nt){
            short8 bh = *(const short8*)&sWH[(nt*16 + col)*264 + dko];
            short8 bl = *(const short8*)&sWL[(nt*16 + col)*264 + dko];
            acc[nt] = MFMA16(al, bh, acc[nt]);
            acc[nt] = MFMA16(ah, bl, acc[nt]);
            acc[nt] = MFMA16(ah, bh, acc[nt]);
        }
    }
    #pragma unroll
    for (int nt = 0; nt < 2; ++nt){
        const int dk = nt*16 + col;
        #pragma unroll
        for (int r = 0; r < 4; ++r){
            const int t = t0 + w*16 + quad*4 + r;
            float v = acc[nt][r];
            short h = f2bf(v);
            size_t o = (size_t)(((b*NH + j)*NTQ + t)*NDK + dk);
            OH[o] = h; OL[o] = f2bf(v - bf2f(h));
        }
    }
}

// ---------------- kernel 2: attention (R6 16-q body) + tail-elected final MLP ----------------
// grid (16, 8, 16): x = q-tile (16 rows), y = j, z = b. 256 thr = 4 waves.
// After HD write: device-scope atomic on cnt[b*16+x]; 8th arriver (all j done for
// this (b,qtile)) runs the final MLP for rows t0..t0+15 (R6-final arithmetic verbatim).
__global__ __launch_bounds__(256, 4)
void imta_at(char* __restrict__ wsb, const float* __restrict__ value,
             const float* __restrict__ Wc, const float* __restrict__ bc,
             const float* __restrict__ Wo1, const float* __restrict__ bo1,
             const float* __restrict__ Wo2, const float* __restrict__ bo2,
             float* __restrict__ out){
    const int t0 = blockIdx.x*16;
    const int j = blockIdx.y, b = blockIdx.z;
    const int tid = threadIdx.x, w = tid >> 6, lane = tid & 63;
    const int col = lane & 15, quad = lane >> 4;
    __shared__ __align__(16) char sMem[19648];     // union: sE[16][264]s | sHD2[16*288]f + sW1[216]f
    __shared__ int sLast;
    short* const sE = (short*)sMem;
    const short* QH = (const short*)(wsb + QPH_OFF) + (b*NH + j)*NTQ*NDK;
    const short* QL = (const short*)(wsb + QPL_OFF) + (b*NH + j)*NTQ*NDK;
    const short* KH = (const short*)(wsb + KPH_OFF) + (b*NH + j)*NTK*NDK;
    const short* KL = (const short*)(wsb + KPL_OFF) + (b*NH + j)*NTK*NDK;
    const short* RT = (const short*)(wsb + RT_OFF) + b*80*256;
    float* HD = (float*)(wsb + HD_OFF) + (b*NH + j)*NTQ*NF;

    // ---- phase 1: scores -> exp -> sE (R6 verbatim) ----
    short8 ah = ld8(QH + (t0 + col)*NDK + quad*8);
    short8 al = ld8(QL + (t0 + col)*NDK + quad*8);
    #pragma unroll
    for (int nt = 0; nt < 4; ++nt){
        const int key0 = w*64 + nt*16;
        short8 bh = ld8(KH + (key0 + col)*NDK + quad*8);
        short8 bl = ld8(KL + (key0 + col)*NDK + quad*8);
        f32x4 c = (f32x4)0.f;
        c = MFMA16(al, bh, c);
        c = MFMA16(ah, bl, c);
        c = MFMA16(ah, bh, c);
        const int key = key0 + col;
        #pragma unroll
        for (int r = 0; r < 4; ++r)
            sE[(quad*4 + r)*264 + key] = f2bf(__expf(c[r]));
    }
    __syncthreads();

    // ---- phase 2: E @ RT (R6 verbatim) ----
    f32x4 accA = (f32x4)0.f, accB = (f32x4)0.f;
    #pragma unroll 2
    for (int kb = 0; kb < 8; ++kb){
        const int ko = kb*32 + quad*8;
        short8 a = *(const short8*)&sE[col*264 + ko];
        short8 bb = ld8(RT + (w*16 + col)*256 + ko);
        accA = MFMA16(a, bb, accA);
        if (w == 0){
            short8 b2 = ld8(RT + (64 + col)*256 + ko);
            accB = MFMA16(a, b2, accB);
        }
    }
    __syncthreads();                           // all phase-2 sE reads done
    float* sH = (float*)sMem;                  // [16][40] heads staging (overlay)
    #pragma unroll
    for (int r = 0; r < 4; ++r){
        float v = accA[r];
        float o = __shfl_xor(v, 1, 64);
        if (!(col & 1)){
            const int f = w*8 + (col >> 1);
            float num = v, den = o, h;
            if (den != 0.0f) h = num/den;
            else {
                float s = 0.f;
                for (int k = 0; k < NTK; ++k) s += value[(b*NTK + k)*NF + f];
                h = s * (1.0f/256.0f);
            }
            sH[(quad*4 + r)*40 + f] = h;
        }
    }
    if (w == 0){
        #pragma unroll
        for (int r = 0; r < 4; ++r){
            float v = accB[r];
            float o = __shfl_xor(v, 1, 64);
            if (!(col & 1)){
                const int f = 32 + (col >> 1);
                if (f < NF){
                    float num = v, den = o, h;
                    if (den != 0.0f) h = num/den;
                    else {
                        float s = 0.f;
                        for (int k = 0; k < NTK; ++k) s += value[(b*NTK + k)*NF + f];
                        h = s * (1.0f/256.0f);
                    }
                    sH[(quad*4 + r)*40 + f] = h;
                }
            }
        }
    }
    __syncthreads();
    for (int idx = tid; idx < 16*NF; idx += 256){
        const int q = idx/NF, f = idx - q*NF;
        HD[(t0 + q)*NF + f] = sH[q*40 + f];
    }

    // ---- tail election: 8th arriver of (b, qtile) runs the final MLP ----
    __syncthreads();                           // all HD stores drained (vmcnt0 before barrier)
    if (tid == 0){
        __threadfence();                       // release: L2 writeback, device scope
        unsigned old = __hip_atomic_fetch_add(
            (unsigned*)(wsb + CNT_OFF) + (b*16 + blockIdx.x), 1u,
            __ATOMIC_ACQ_REL, __HIP_MEMORY_SCOPE_AGENT);
        sLast = (old == 7u) ? 1 : 0;
    }
    __syncthreads();
    if (!sLast) return;
    __threadfence();                           // acquire: invalidate caches before HD reads

    // stage HD[all j][t0..t0+15] -> LDS [q][jj*36+f] (R6-final layout per q)
    const float* hdall = (const float*)(wsb + HD_OFF);
    float* const sHD2 = (float*)sMem;          // 16*288 floats
    float* const sW1  = sHD2 + 16*288;         // 216 floats
    for (int idx = tid; idx < 16*NF*NH; idx += 256){
        const int q = idx/(NF*NH), r = idx - q*(NF*NH);
        const int jj = r/NF, f = r - jj*NF;
        sHD2[q*288 + jj*NF + f] = hdall[((size_t)(b*NH + jj)*NTQ + t0 + q)*NF + f];
    }
    if (tid < NF*NSF) sW1[tid] = Wo1[tid];
    __syncthreads();

    // final MLP (R6-final arithmetic verbatim), thread = d, loop 16 q rows
    {
        const int d = tid;
        float wcr[8];
        #pragma unroll
        for (int h = 0; h < 8; ++h) wcr[h] = Wc[h*ND + d];
        const float bcd = bc[d];
        float bo1r[6], wo2r[6];
        #pragma unroll
        for (int s = 0; s < 6; ++s){ bo1r[s] = bo1[s]; wo2r[s] = Wo2[s]; }
        const float bo2d = bo2[d];
        for (int q = 0; q < 16; ++q){
            const float* shq = sHD2 + q*288;
            float a2[6];
            #pragma unroll
            for (int s = 0; s < 6; ++s) a2[s] = bo1r[s];
            #pragma unroll
            for (int f4 = 0; f4 < NF; f4 += 4){
                float4 sv[8];
                #pragma unroll
                for (int h = 0; h < 8; ++h) sv[h] = *(const float4*)&shq[h*NF + f4];
                #pragma unroll
                for (int fi = 0; fi < 4; ++fi){
                    float a = bcd;
                    #pragma unroll
                    for (int h = 0; h < 8; ++h)
                        a = fmaf(reinterpret_cast<const float*>(&sv[h])[fi], wcr[h], a);
                    float lf = fast_tanh(a);
                    const int f = f4 + fi;
                    #pragma unroll
                    for (int s = 0; s < 6; ++s)
                        a2[s] = fmaf(lf, sW1[f*NSF + s], a2[s]);
                }
            }
            float o = bo2d;
            #pragma unroll
            for (int s = 0; s < 6; ++s)
                o = fmaf(fast_tanh(a2[s]), wo2r[s], o);
            out[(b*NTQ + t0 + q)*ND + d] = o;
        }
    }
}

extern "C" void kernel_launch(void* const* d_in, const int* in_sizes, int n_in,
                              void* d_out, int out_size, void* d_ws, size_t ws_size,
                              hipStream_t stream){
    const float* query  = (const float*)d_in[0];
    const float* key_ts = (const float*)d_in[1];
    const float* value  = (const float*)d_in[2];
    const float* mask   = (const float*)d_in[3];
    const float* Wq     = (const float*)d_in[4];
    const float* Wk     = (const float*)d_in[5];
    const float* Wc     = (const float*)d_in[6];
    const float* bc     = (const float*)d_in[7];
    const float* Wo1    = (const float*)d_in[8];
    const float* bo1    = (const float*)d_in[9];
    const float* Wo2    = (const float*)d_in[10];
    const float* bo2    = (const float*)d_in[11];
    char* wsb  = (char*)d_ws;
    float* out = (float*)d_out;
    (void)in_sizes; (void)n_in; (void)out_size; (void)ws_size;

    imta_proj<<<dim3(1280),      dim3(256), 0, stream>>>(query, key_ts, Wq, Wk, mask, value, wsb);
    imta_at  <<<dim3(16, 8, 16), dim3(256), 0, stream>>>(wsb, value, Wc, bc, Wo1, bo1, Wo2, bo2, out);
}

// Round 10
// 149.760 us; speedup vs baseline: 3.5936x; 3.5936x over previous
//
#include <hip/hip_runtime.h>

#define NB 16
#define NTQ 256
#define NTK 256
#define ND 256
#define NF 36
#define NH 8
#define NDK 32
#define NSF 6

typedef __attribute__((ext_vector_type(8))) short short8;
typedef __attribute__((ext_vector_type(4))) float f32x4;
#define MFMA16(a,b,c) __builtin_amdgcn_mfma_f32_16x16x32_bf16(a,b,c,0,0,0)

// ---- workspace byte offsets ----
// WqT hi/lo: [j*32+dk][d] bf16, 128KB each
#define WQTH_OFF 0u
#define WQTL_OFF 131072u
// RT: [b][80][256] bf16 (f'=2f: m*v, f'=2f+1: m)
#define RT_OFF   524288u
// projected K hi/lo: [b][j][t][dk] bf16, 4MB each
#define KPH_OFF  (10u*1024*1024)
#define KPL_OFF  (14u*1024*1024)
// HD: fp32 [b][j][t][f]
#define HD_OFF   (18u*1024*1024)

__device__ __forceinline__ short f2bf(float x){
    union { float f; unsigned u; } v; v.f = x;
    unsigned r = v.u + 0x7fffu + ((v.u >> 16) & 1u);
    return (short)(r >> 16);
}
__device__ __forceinline__ float bf2f(short s){
    union { float f; unsigned u; } v; v.u = ((unsigned)(unsigned short)s) << 16;
    return v.f;
}
__device__ __forceinline__ float fast_tanh(float x){
    float e = __expf(2.0f*x);
    return 1.0f - 2.0f/(e + 1.0f);
}
__device__ __forceinline__ short8 ld8(const short* p){ return *(const short8*)p; }

// hi/lo bf16 split of 8 consecutive floats (RNE hi, RNE residual lo)
__device__ __forceinline__ void cvt8(const float* __restrict__ p, short8& h8, short8& l8){
    f32x4 a = *(const f32x4*)p;
    f32x4 c = *(const f32x4*)(p + 4);
    #pragma unroll
    for (int i = 0; i < 4; ++i){
        short h0 = f2bf(a[i]); h8[i]   = h0; l8[i]   = f2bf(a[i] - bf2f(h0));
        short h1 = f2bf(c[i]); h8[4+i] = h1; l8[4+i] = f2bf(c[i] - bf2f(h1));
    }
}

// ---------------- kernel 1: K projection (W staged in LDS) + RT pack + WqT pack ----------------
// bid < 512: K-proj (R6 body, key side only). b=bid>>5, j=(bid>>2)&7, t0=(bid&3)*64.
// bid >= 512: RT pack (verbatim) + WqT transpose/hi-lo pack (65536 elems over 256 blocks).
__global__ __launch_bounds__(256, 4)
void imta_prep(const float* __restrict__ key_ts, const float* __restrict__ Wq,
               const float* __restrict__ Wk, const float* __restrict__ mask,
               const float* __restrict__ value, char* __restrict__ wsb){
    const int bid = blockIdx.x, tid = threadIdx.x;
    if (bid >= 512){
        const int rb = bid - 512;
        // WqT pack: idx = jdk*256 + d
        {
            const int idx = rb*256 + tid;
            const int d = idx & 255, jdk = idx >> 8;
            const int jj = jdk >> 5, dk = jdk & 31;
            float v = Wq[(jj*ND + d)*NDK + dk];
            short h = f2bf(v);
            ((short*)(wsb + WQTH_OFF))[idx] = h;
            ((short*)(wsb + WQTL_OFF))[idx] = f2bf(v - bf2f(h));
        }
        // RT pack (verbatim)
        const int x = rb & 15, b = rb >> 4;
        const int k = tid;
        short* rt = (short*)(wsb + RT_OFF) + b*80*256;
        #pragma unroll
        for (int r = 0; r < 5; ++r){
            const int fp = x*5 + r;
            const int f = fp >> 1;
            short o = 0;
            if (f < NF){
                float m = mask[(b*NTK + k)*NF + f];
                o = (fp & 1) ? f2bf(m) : f2bf(m * value[(b*NTK + k)*NF + f]);
            }
            rt[fp*256 + k] = o;
        }
        return;
    }
    const int b = bid >> 5, j = (bid >> 2) & 7;
    const int t0 = (bid & 3)*64;
    const int w = tid >> 6, lane = tid & 63;
    const int col = lane & 15, quad = lane >> 4;

    __shared__ __align__(16) short sW[2*32*264];     // hi | lo, [dk][264-padded d]
    short* const sWH = sW;
    short* const sWL = sW + 32*264;

    const float* __restrict__ W = Wk + (size_t)j*ND*NDK;
    short* OH = (short*)(wsb + KPH_OFF);
    short* OL = (short*)(wsb + KPL_OFF);

    {
        const int dk0 = (tid & 7)*4, dbase = tid >> 3;
        #pragma unroll
        for (int it = 0; it < 8; ++it){
            const int d = dbase + it*32;
            f32x4 wv = *(const f32x4*)(W + (size_t)d*NDK + dk0);
            #pragma unroll
            for (int i = 0; i < 4; ++i){
                short h = f2bf(wv[i]);
                sWH[(dk0 + i)*264 + d] = h;
                sWL[(dk0 + i)*264 + d] = f2bf(wv[i] - bf2f(h));
            }
        }
    }
    __syncthreads();

    const int row = t0 + w*16 + col;
    const float* xrow = key_ts + (size_t)(b*NTK + row)*ND;
    f32x4 acc[2]; acc[0] = (f32x4)0.f; acc[1] = (f32x4)0.f;
    #pragma unroll
    for (int kb = 0; kb < 8; ++kb){
        const int dko = kb*32 + quad*8;
        short8 ah, al;
        cvt8(xrow + dko, ah, al);
        #pragma unroll
        for (int nt = 0; nt < 2; ++nt){
            short8 bh = *(const short8*)&sWH[(nt*16 + col)*264 + dko];
            short8 bl = *(const short8*)&sWL[(nt*16 + col)*264 + dko];
            acc[nt] = MFMA16(al, bh, acc[nt]);
            acc[nt] = MFMA16(ah, bl, acc[nt]);
            acc[nt] = MFMA16(ah, bh, acc[nt]);
        }
    }
    #pragma unroll
    for (int nt = 0; nt < 2; ++nt){
        const int dk = nt*16 + col;
        #pragma unroll
        for (int r = 0; r < 4; ++r){
            const int t = t0 + w*16 + quad*4 + r;
            float v = acc[nt][r];
            short h = f2bf(v);
            size_t o = (size_t)(((b*NH + j)*NTQ + t)*NDK + dk);
            OH[o] = h; OL[o] = f2bf(v - bf2f(h));
        }
    }
}

// ---------------- kernel 2: attention with inline Q-projection (16-q, 2048 blocks) ----------------
// grid (16, 8, 16): x = q-tile (16 rows), y = j, z = b. 256 thr = 4 waves.
// phase0: waves 0,1 project Q rows t0..t0+15 (wave w -> dk tile nt=w) -> sQ hi/lo LDS.
// phase1: wave w -> keys [64w, 64w+64) (3-pass hi/lo scores) -> exp -> sE (R6 verbatim).
// phase2: wave w -> f-tile nt=w (wave 0 also nt=4), full K; shfl div -> sH -> HD (R6 verbatim).
__global__ __launch_bounds__(256, 8)
void imta_attn(char* __restrict__ wsb, const float* __restrict__ query,
               const float* __restrict__ value){
    const int t0 = blockIdx.x*16;
    const int j = blockIdx.y, b = blockIdx.z;
    const int tid = threadIdx.x, w = tid >> 6, lane = tid & 63;
    const int col = lane & 15, quad = lane >> 4;
    __shared__ __align__(16) short sE[16*264];     // 8.25 KB; overlaid by sH
    __shared__ __align__(16) short sQH[16*40];     // 1.25 KB each, stride 40 (80B, 16B-aligned)
    __shared__ __align__(16) short sQL[16*40];
    const short* KH = (const short*)(wsb + KPH_OFF) + (b*NH + j)*NTK*NDK;
    const short* KL = (const short*)(wsb + KPL_OFF) + (b*NH + j)*NTK*NDK;
    const short* RT = (const short*)(wsb + RT_OFF) + b*80*256;
    float* HD = (float*)(wsb + HD_OFF) + (b*NH + j)*NTQ*NF;

    // ---- phase 0: inline Q projection (waves 0,1), same MFMA order as prep ----
    if (w < 2){
        const short* WTH = (const short*)(wsb + WQTH_OFF) + (size_t)(j*32 + w*16 + col)*ND;
        const short* WTL = (const short*)(wsb + WQTL_OFF) + (size_t)(j*32 + w*16 + col)*ND;
        const float* xrow = query + (size_t)(b*NTQ + t0 + col)*ND;
        f32x4 qa = (f32x4)0.f;
        #pragma unroll
        for (int kb = 0; kb < 8; ++kb){
            const int dko = kb*32 + quad*8;
            short8 xh, xl;
            cvt8(xrow + dko, xh, xl);
            short8 bh = ld8(WTH + dko);
            short8 bl = ld8(WTL + dko);
            qa = MFMA16(xl, bh, qa);
            qa = MFMA16(xh, bl, qa);
            qa = MFMA16(xh, bh, qa);
        }
        const int dk = w*16 + col;
        #pragma unroll
        for (int r = 0; r < 4; ++r){
            const int q = quad*4 + r;
            float v = qa[r];
            short h = f2bf(v);
            sQH[q*40 + dk] = h;
            sQL[q*40 + dk] = f2bf(v - bf2f(h));
        }
    }
    __syncthreads();

    // ---- phase 1: scores -> exp -> sE (R6 verbatim, Q frags from LDS) ----
    short8 ah = *(const short8*)&sQH[col*40 + quad*8];
    short8 al = *(const short8*)&sQL[col*40 + quad*8];
    #pragma unroll
    for (int nt = 0; nt < 4; ++nt){
        const int key0 = w*64 + nt*16;
        short8 bh = ld8(KH + (key0 + col)*NDK + quad*8);
        short8 bl = ld8(KL + (key0 + col)*NDK + quad*8);
        f32x4 c = (f32x4)0.f;
        c = MFMA16(al, bh, c);
        c = MFMA16(ah, bl, c);
        c = MFMA16(ah, bh, c);
        const int key = key0 + col;
        #pragma unroll
        for (int r = 0; r < 4; ++r)
            sE[(quad*4 + r)*264 + key] = f2bf(__expf(c[r]));
    }
    __syncthreads();

    // ---- phase 2: E @ RT (R6 verbatim) ----
    f32x4 accA = (f32x4)0.f, accB = (f32x4)0.f;
    #pragma unroll 2
    for (int kb = 0; kb < 8; ++kb){
        const int ko = kb*32 + quad*8;
        short8 a = *(const short8*)&sE[col*264 + ko];
        short8 bb = ld8(RT + (w*16 + col)*256 + ko);
        accA = MFMA16(a, bb, accA);
        if (w == 0){
            short8 b2 = ld8(RT + (64 + col)*256 + ko);
            accB = MFMA16(a, b2, accB);
        }
    }
    __syncthreads();                           // all phase-2 sE reads done
    float* sH = (float*)sE;                    // [16][40] heads staging
    #pragma unroll
    for (int r = 0; r < 4; ++r){
        float v = accA[r];
        float o = __shfl_xor(v, 1, 64);
        if (!(col & 1)){
            const int f = w*8 + (col >> 1);
            float num = v, den = o, h;
            if (den != 0.0f) h = num/den;
            else {
                float s = 0.f;
                for (int k = 0; k < NTK; ++k) s += value[(b*NTK + k)*NF + f];
                h = s * (1.0f/256.0f);
            }
            sH[(quad*4 + r)*40 + f] = h;
        }
    }
    if (w == 0){
        #pragma unroll
        for (int r = 0; r < 4; ++r){
            float v = accB[r];
            float o = __shfl_xor(v, 1, 64);
            if (!(col & 1)){
                const int f = 32 + (col >> 1);
                if (f < NF){
                    float num = v, den = o, h;
                    if (den != 0.0f) h = num/den;
                    else {
                        float s = 0.f;
                        for (int k = 0; k < NTK; ++k) s += value[(b*NTK + k)*NF + f];
                        h = s * (1.0f/256.0f);
                    }
                    sH[(quad*4 + r)*40 + f] = h;
                }
            }
        }
    }
    __syncthreads();
    for (int idx = tid; idx < 16*NF; idx += 256){
        const int q = idx/NF, f = idx - q*NF;
        HD[(t0 + q)*NF + f] = sH[q*40 + f];
    }
}

// ---------------- kernel 3: fused head-mix MLP (R6 verbatim) ----------------
__global__ void imta_final(const float* __restrict__ Wc, const float* __restrict__ bc,
                           const float* __restrict__ Wo1, const float* __restrict__ bo1,
                           const float* __restrict__ Wo2, const float* __restrict__ bo2,
                           const float* __restrict__ hd, float* __restrict__ out){
    const int bq = blockIdx.x;
    const int b = bq >> 8, qq = bq & 255;
    const int tid = threadIdx.x;
    __shared__ float sh[NF*NH];
    __shared__ float sW1[NF*NSF];
    for (int t = tid; t < NF*NH; t += 256){
        int jj = t/NF, f = t - jj*NF;
        sh[t] = hd[((b*NH + jj)*NTQ + qq)*NF + f];
    }
    if (tid < NF*NSF) sW1[tid] = Wo1[tid];
    __syncthreads();
    const int d = tid;
    float wcr[8];
    #pragma unroll
    for (int h = 0; h < 8; ++h) wcr[h] = Wc[h*ND + d];
    const float bcd = bc[d];
    float a2[6];
    #pragma unroll
    for (int s = 0; s < 6; ++s) a2[s] = bo1[s];
    #pragma unroll
    for (int f4 = 0; f4 < NF; f4 += 4){
        float4 sv[8];
        #pragma unroll
        for (int h = 0; h < 8; ++h) sv[h] = *(const float4*)&sh[h*NF + f4];
        #pragma unroll
        for (int fi = 0; fi < 4; ++fi){
            float a = bcd;
            #pragma unroll
            for (int h = 0; h < 8; ++h)
                a = fmaf(reinterpret_cast<const float*>(&sv[h])[fi], wcr[h], a);
            float lf = fast_tanh(a);
            const int f = f4 + fi;
            #pragma unroll
            for (int s = 0; s < 6; ++s)
                a2[s] = fmaf(lf, sW1[f*NSF + s], a2[s]);
        }
    }
    float o = bo2[d];
    #pragma unroll
    for (int s = 0; s < 6; ++s)
        o = fmaf(fast_tanh(a2[s]), Wo2[s], o);
    out[(b*NTQ + qq)*ND + d] = o;
}

extern "C" void kernel_launch(void* const* d_in, const int* in_sizes, int n_in,
                              void* d_out, int out_size, void* d_ws, size_t ws_size,
                              hipStream_t stream){
    const float* query  = (const float*)d_in[0];
    const float* key_ts = (const float*)d_in[1];
    const float* value  = (const float*)d_in[2];
    const float* mask   = (const float*)d_in[3];
    const float* Wq     = (const float*)d_in[4];
    const float* Wk     = (const float*)d_in[5];
    const float* Wc     = (const float*)d_in[6];
    const float* bc     = (const float*)d_in[7];
    const float* Wo1    = (const float*)d_in[8];
    const float* bo1    = (const float*)d_in[9];
    const float* Wo2    = (const float*)d_in[10];
    const float* bo2    = (const float*)d_in[11];
    char* wsb  = (char*)d_ws;
    float* out = (float*)d_out;
    (void)in_sizes; (void)n_in; (void)out_size; (void)ws_size;

    imta_prep <<<dim3(768),      dim3(256), 0, stream>>>(key_ts, Wq, Wk, mask, value, wsb);
    imta_attn <<<dim3(16, 8, 16),dim3(256), 0, stream>>>(wsb, query, value);
    imta_final<<<dim3(4096),     dim3(256), 0, stream>>>(Wc, bc, Wo1, bo1, Wo2, bo2,
                                                         (const float*)(wsb + HD_OFF), out);
}

// Round 11
// 141.243 us; speedup vs baseline: 3.8103x; 1.0603x over previous
//
#include <hip/hip_runtime.h>

#define NB 16
#define NTQ 256
#define NTK 256
#define ND 256
#define NF 36
#define NH 8
#define NDK 32
#define NSF 6

typedef __attribute__((ext_vector_type(8))) short short8;
typedef __attribute__((ext_vector_type(4))) float f32x4;
#define MFMA16(a,b,c) __builtin_amdgcn_mfma_f32_16x16x32_bf16(a,b,c,0,0,0)

// ---- workspace byte offsets ----
// RT: [b][80][256] bf16 (f'=2f: m*v, f'=2f+1: m)
#define RT_OFF   524288u
// projected Q/K hi/lo: [b][j][t][dk] bf16, 4MB each
#define QPH_OFF  (2u*1024*1024)
#define QPL_OFF  (6u*1024*1024)
#define KPH_OFF  (10u*1024*1024)
#define KPL_OFF  (14u*1024*1024)
// HD: fp32 [b][j][t][f]
#define HD_OFF   (18u*1024*1024)

__device__ __forceinline__ short f2bf(float x){
    union { float f; unsigned u; } v; v.f = x;
    unsigned r = v.u + 0x7fffu + ((v.u >> 16) & 1u);
    return (short)(r >> 16);
}
__device__ __forceinline__ float bf2f(short s){
    union { float f; unsigned u; } v; v.u = ((unsigned)(unsigned short)s) << 16;
    return v.f;
}
__device__ __forceinline__ float fast_tanh(float x){
    float e = __expf(2.0f*x);
    return 1.0f - 2.0f/(e + 1.0f);
}
__device__ __forceinline__ short8 ld8(const short* p){ return *(const short8*)p; }

// hi/lo bf16 split of 8 consecutive floats (RNE hi, RNE residual lo)
__device__ __forceinline__ void cvt8(const float* __restrict__ p, short8& h8, short8& l8){
    f32x4 a = *(const f32x4*)p;
    f32x4 c = *(const f32x4*)(p + 4);
    #pragma unroll
    for (int i = 0; i < 4; ++i){
        short h0 = f2bf(a[i]); h8[i]   = h0; l8[i]   = f2bf(a[i] - bf2f(h0));
        short h1 = f2bf(c[i]); h8[4+i] = h1; l8[4+i] = f2bf(c[i] - bf2f(h1));
    }
}

// ---------------- kernel 1: projection GEMM (W staged in LDS) + RT pack ----------------
// bid < 1024: proj. b=bid>>6, side=(bid>>5)&1, j=(bid>>2)&7, t0=(bid&3)*64.
//   Stage W[j] (fp32, global) -> LDS hi/lo [dk][d] once (1 barrier), then wave w
//   computes rows [t0+16w, t0+16w+16) x 32 cols: per kb {cvt8(X) ; 2x ld8 LDS ; 6 MFMA}.
//   Same per-output MFMA accumulation order as verified rounds -> bit-identical.
// bid >= 1024: RT pack (verbatim).
__global__ __launch_bounds__(256, 4)
void imta_proj(const float* __restrict__ query, const float* __restrict__ key_ts,
               const float* __restrict__ Wq, const float* __restrict__ Wk,
               const float* __restrict__ mask, const float* __restrict__ value,
               char* __restrict__ wsb){
    const int bid = blockIdx.x, tid = threadIdx.x;
    if (bid >= 1024){
        const int rb = bid - 1024;
        const int x = rb & 15, b = rb >> 4;
        const int k = tid;
        short* rt = (short*)(wsb + RT_OFF) + b*80*256;
        #pragma unroll
        for (int r = 0; r < 5; ++r){
            const int fp = x*5 + r;
            const int f = fp >> 1;
            short o = 0;
            if (f < NF){
                float m = mask[(b*NTK + k)*NF + f];
                o = (fp & 1) ? f2bf(m) : f2bf(m * value[(b*NTK + k)*NF + f]);
            }
            rt[fp*256 + k] = o;
        }
        return;
    }
    const int b = bid >> 6, side = (bid >> 5) & 1, j = (bid >> 2) & 7;
    const int t0 = (bid & 3)*64;
    const int w = tid >> 6, lane = tid & 63;
    const int col = lane & 15, quad = lane >> 4;

    __shared__ __align__(16) short sW[2*32*264];     // hi | lo, [dk][264-padded d]
    short* const sWH = sW;
    short* const sWL = sW + 32*264;

    const float* __restrict__ X = side ? key_ts : query;
    const float* __restrict__ W = (side ? Wk : Wq) + (size_t)j*ND*NDK;
    short* OH = (short*)(wsb + (side ? KPH_OFF : QPH_OFF));
    short* OL = (short*)(wsb + (side ? KPL_OFF : QPL_OFF));

    {
        const int dk0 = (tid & 7)*4, dbase = tid >> 3;
        #pragma unroll
        for (int it = 0; it < 8; ++it){
            const int d = dbase + it*32;
            f32x4 wv = *(const f32x4*)(W + (size_t)d*NDK + dk0);
            #pragma unroll
            for (int i = 0; i < 4; ++i){
                short h = f2bf(wv[i]);
                sWH[(dk0 + i)*264 + d] = h;
                sWL[(dk0 + i)*264 + d] = f2bf(wv[i] - bf2f(h));
            }
        }
    }
    __syncthreads();

    const int row = t0 + w*16 + col;
    const float* xrow = X + (size_t)(b*NTQ + row)*ND;
    f32x4 acc[2]; acc[0] = (f32x4)0.f; acc[1] = (f32x4)0.f;
    #pragma unroll
    for (int kb = 0; kb < 8; ++kb){
        const int dko = kb*32 + quad*8;
        short8 ah, al;
        cvt8(xrow + dko, ah, al);
        #pragma unroll
        for (int nt = 0; nt < 2; ++nt){
            short8 bh = *(const short8*)&sWH[(nt*16 + col)*264 + dko];
            short8 bl = *(const short8*)&sWL[(nt*16 + col)*264 + dko];
            acc[nt] = MFMA16(al, bh, acc[nt]);
            acc[nt] = MFMA16(ah, bl, acc[nt]);
            acc[nt] = MFMA16(ah, bh, acc[nt]);
        }
    }
    #pragma unroll
    for (int nt = 0; nt < 2; ++nt){
        const int dk = nt*16 + col;
        #pragma unroll
        for (int r = 0; r < 4; ++r){
            const int t = t0 + w*16 + quad*4 + r;
            float v = acc[nt][r];
            short h = f2bf(v);
            size_t o = (size_t)(((b*NH + j)*NTQ + t)*NDK + dk);
            OH[o] = h; OL[o] = f2bf(v - bf2f(h));
        }
    }
}

// ---------------- kernel 2: attention (16-q, 2048 blocks, full occupancy) ----------------
// grid (16, 8, 16): x = q-tile (16 rows), y = j, z = b. 256 thr = 4 waves.
// phase1: wave w -> keys [64w, 64w+64) (3-pass hi/lo scores) -> exp -> sE
// phase2: wave w -> f-tile nt=w (wave 0 also nt=4), full K; shfl div -> sH -> HD
__global__ __launch_bounds__(256, 8)
void imta_attn(char* __restrict__ wsb, const float* __restrict__ value){
    const int t0 = blockIdx.x*16;
    const int j = blockIdx.y, b = blockIdx.z;
    const int tid = threadIdx.x, w = tid >> 6, lane = tid & 63;
    const int col = lane & 15, quad = lane >> 4;
    __shared__ __align__(16) short sE[16*264];     // 8.25 KB; overlaid by sH
    const short* QH = (const short*)(wsb + QPH_OFF) + (b*NH + j)*NTQ*NDK;
    const short* QL = (const short*)(wsb + QPL_OFF) + (b*NH + j)*NTQ*NDK;
    const short* KH = (const short*)(wsb + KPH_OFF) + (b*NH + j)*NTK*NDK;
    const short* KL = (const short*)(wsb + KPL_OFF) + (b*NH + j)*NTK*NDK;
    const short* RT = (const short*)(wsb + RT_OFF) + b*80*256;
    float* HD = (float*)(wsb + HD_OFF) + (b*NH + j)*NTQ*NF;

    short8 ah = ld8(QH + (t0 + col)*NDK + quad*8);
    short8 al = ld8(QL + (t0 + col)*NDK + quad*8);
    #pragma unroll
    for (int nt = 0; nt < 4; ++nt){
        const int key0 = w*64 + nt*16;
        short8 bh = ld8(KH + (key0 + col)*NDK + quad*8);
        short8 bl = ld8(KL + (key0 + col)*NDK + quad*8);
        f32x4 c = (f32x4)0.f;
        c = MFMA16(al, bh, c);
        c = MFMA16(ah, bl, c);
        c = MFMA16(ah, bh, c);
        const int key = key0 + col;
        #pragma unroll
        for (int r = 0; r < 4; ++r)
            sE[(quad*4 + r)*264 + key] = f2bf(__expf(c[r]));
    }
    __syncthreads();

    f32x4 accA = (f32x4)0.f, accB = (f32x4)0.f;
    #pragma unroll 2
    for (int kb = 0; kb < 8; ++kb){
        const int ko = kb*32 + quad*8;
        short8 a = *(const short8*)&sE[col*264 + ko];
        short8 bb = ld8(RT + (w*16 + col)*256 + ko);
        accA = MFMA16(a, bb, accA);
        if (w == 0){
            short8 b2 = ld8(RT + (64 + col)*256 + ko);
            accB = MFMA16(a, b2, accB);
        }
    }
    __syncthreads();                           // all phase-2 sE reads done
    float* sH = (float*)sE;                    // [16][40] heads staging
    #pragma unroll
    for (int r = 0; r < 4; ++r){
        float v = accA[r];
        float o = __shfl_xor(v, 1, 64);
        if (!(col & 1)){
            const int f = w*8 + (col >> 1);
            float num = v, den = o, h;
            if (den != 0.0f) h = num/den;
            else {
                float s = 0.f;
                for (int k = 0; k < NTK; ++k) s += value[(b*NTK + k)*NF + f];
                h = s * (1.0f/256.0f);
            }
            sH[(quad*4 + r)*40 + f] = h;
        }
    }
    if (w == 0){
        #pragma unroll
        for (int r = 0; r < 4; ++r){
            float v = accB[r];
            float o = __shfl_xor(v, 1, 64);
            if (!(col & 1)){
                const int f = 32 + (col >> 1);
                if (f < NF){
                    float num = v, den = o, h;
                    if (den != 0.0f) h = num/den;
                    else {
                        float s = 0.f;
                        for (int k = 0; k < NTK; ++k) s += value[(b*NTK + k)*NF + f];
                        h = s * (1.0f/256.0f);
                    }
                    sH[(quad*4 + r)*40 + f] = h;
                }
            }
        }
    }
    __syncthreads();
    for (int idx = tid; idx < 16*NF; idx += 256){
        const int q = idx/NF, f = idx - q*NF;
        HD[(t0 + q)*NF + f] = sH[q*40 + f];
    }
}

// ---------------- kernel 3: fused head-mix MLP ----------------
__global__ void imta_final(const float* __restrict__ Wc, const float* __restrict__ bc,
                           const float* __restrict__ Wo1, const float* __restrict__ bo1,
                           const float* __restrict__ Wo2, const float* __restrict__ bo2,
                           const float* __restrict__ hd, float* __restrict__ out){
    const int bq = blockIdx.x;
    const int b = bq >> 8, qq = bq & 255;
    const int tid = threadIdx.x;
    __shared__ float sh[NF*NH];
    __shared__ float sW1[NF*NSF];
    for (int t = tid; t < NF*NH; t += 256){
        int jj = t/NF, f = t - jj*NF;
        sh[t] = hd[((b*NH + jj)*NTQ + qq)*NF + f];
    }
    if (tid < NF*NSF) sW1[tid] = Wo1[tid];
    __syncthreads();
    const int d = tid;
    float wcr[8];
    #pragma unroll
    for (int h = 0; h < 8; ++h) wcr[h] = Wc[h*ND + d];
    const float bcd = bc[d];
    float a2[6];
    #pragma unroll
    for (int s = 0; s < 6; ++s) a2[s] = bo1[s];
    #pragma unroll
    for (int f4 = 0; f4 < NF; f4 += 4){
        float4 sv[8];
        #pragma unroll
        for (int h = 0; h < 8; ++h) sv[h] = *(const float4*)&sh[h*NF + f4];
        #pragma unroll
        for (int fi = 0; fi < 4; ++fi){
            float a = bcd;
            #pragma unroll
            for (int h = 0; h < 8; ++h)
                a = fmaf(reinterpret_cast<const float*>(&sv[h])[fi], wcr[h], a);
            float lf = fast_tanh(a);
            const int f = f4 + fi;
            #pragma unroll
            for (int s = 0; s < 6; ++s)
                a2[s] = fmaf(lf, sW1[f*NSF + s], a2[s]);
        }
    }
    float o = bo2[d];
    #pragma unroll
    for (int s = 0; s < 6; ++s)
        o = fmaf(fast_tanh(a2[s]), Wo2[s], o);
    out[(b*NTQ + qq)*ND + d] = o;
}

extern "C" void kernel_launch(void* const* d_in, const int* in_sizes, int n_in,
                              void* d_out, int out_size, void* d_ws, size_t ws_size,
                              hipStream_t stream){
    const float* query  = (const float*)d_in[0];
    const float* key_ts = (const float*)d_in[1];
    const float* value  = (const float*)d_in[2];
    const float* mask   = (const float*)d_in[3];
    const float* Wq     = (const float*)d_in[4];
    const float* Wk     = (const float*)d_in[5];
    const float* Wc     = (const float*)d_in[6];
    const float* bc     = (const float*)d_in[7];
    const float* Wo1    = (const float*)d_in[8];
    const float* bo1    = (const float*)d_in[9];
    const float* Wo2    = (const float*)d_in[10];
    const float* bo2    = (const float*)d_in[11];
    char* wsb  = (char*)d_ws;
    float* out = (float*)d_out;
    (void)in_sizes; (void)n_in; (void)out_size; (void)ws_size;

    imta_proj <<<dim3(1280),     dim3(256), 0, stream>>>(query, key_ts, Wq, Wk, mask, value, wsb);
    imta_attn <<<dim3(16, 8, 16),dim3(256), 0, stream>>>(wsb, value);
    imta_final<<<dim3(4096),     dim3(256), 0, stream>>>(Wc, bc, Wo1, bo1, Wo2, bo2,
                                                         (const float*)(wsb + HD_OFF), out);
}